// Round 18
// baseline (156.707 us; speedup 1.0000x reference)
//
#include <hip/hip_runtime.h>
#include <stdint.h>

// r13 retro-analysis: 2048-block grid = EXACTLY 1.0x wave capacity -> 55%
// occupancy (no slack, dispatch skew starves SIMDs); r12's 89% occ came from
// 16x-deep grid and masked its +40% redundant calls. THIS ROUND: 4096 blocks
// x 512 threads (8 waves) = 4x capacity, 4 rows/wave, phase-1 = 1 tf/thread
// (+3% total calls). Per-sample stream byte-identical to r17 (dual-chain asm
// threefry + rcp trick; verified absmax 3.8e-6).
// All transcendentals raw-ISA asm — libm compile hangs on this pod.

struct U2 { uint32_t a, b; };
constexpr uint32_t crotl(uint32_t x, int r) { return (x << r) | (x >> (32 - r)); }

constexpr U2 ctf(uint32_t k0, uint32_t k1, uint32_t x0, uint32_t x1) {
  const uint32_t ks2 = k0 ^ k1 ^ 0x1BD11BDAu;
  x0 += k0; x1 += k1;
  x0 += x1; x1 = crotl(x1, 13); x1 ^= x0;
  x0 += x1; x1 = crotl(x1, 15); x1 ^= x0;
  x0 += x1; x1 = crotl(x1, 26); x1 ^= x0;
  x0 += x1; x1 = crotl(x1, 6);  x1 ^= x0;
  x0 += k1;  x1 += ks2 + 1u;
  x0 += x1; x1 = crotl(x1, 17); x1 ^= x0;
  x0 += x1; x1 = crotl(x1, 29); x1 ^= x0;
  x0 += x1; x1 = crotl(x1, 16); x1 ^= x0;
  x0 += x1; x1 = crotl(x1, 24); x1 ^= x0;
  x0 += ks2; x1 += k0 + 2u;
  x0 += x1; x1 = crotl(x1, 13); x1 ^= x0;
  x0 += x1; x1 = crotl(x1, 15); x1 ^= x0;
  x0 += x1; x1 = crotl(x1, 26); x1 ^= x0;
  x0 += x1; x1 = crotl(x1, 6);  x1 ^= x0;
  x0 += k0;  x1 += k1 + 3u;
  x0 += x1; x1 = crotl(x1, 17); x1 ^= x0;
  x0 += x1; x1 = crotl(x1, 29); x1 ^= x0;
  x0 += x1; x1 = crotl(x1, 16); x1 ^= x0;
  x0 += x1; x1 = crotl(x1, 24); x1 ^= x0;
  x0 += k1;  x1 += ks2 + 4u;
  x0 += x1; x1 = crotl(x1, 13); x1 ^= x0;
  x0 += x1; x1 = crotl(x1, 15); x1 ^= x0;
  x0 += x1; x1 = crotl(x1, 26); x1 ^= x0;
  x0 += x1; x1 = crotl(x1, 6);  x1 ^= x0;
  x0 += ks2; x1 += k0 + 5u;
  return U2{x0, x1};
}

constexpr U2 KG1 = ctf(0u, 42u, 0u, 0u);   // g1 (OUT,IN)
constexpr U2 KG2 = ctf(0u, 42u, 0u, 1u);   // g2 (B,OUT,IN)
constexpr uint32_t K0  = KG2.a, K1 = KG2.b;
constexpr uint32_t KS2 = K0 ^ K1 ^ 0x1BD11BDAu;
constexpr uint32_t C1 = KS2 + 1u, C2 = K0 + 2u, C3 = K1 + 3u,
                   C4 = KS2 + 4u, C5 = K0 + 5u;

#define TFR2(S) \
  "v_add_u32 %0,%0,%1\n\t" "v_add_u32 %2,%2,%3\n\t" \
  "v_alignbit_b32 %1,%1,%1," S "\n\t" "v_alignbit_b32 %3,%3,%3," S "\n\t" \
  "v_xor_b32 %1,%1,%0\n\t" "v_xor_b32 %3,%3,%2\n\t"
#define INJ2(KA, KB) \
  "v_add_u32 %0," KA ",%0\n\t" "v_add_u32 %2," KA ",%2\n\t" \
  "v_add_u32 %1," KB ",%1\n\t" "v_add_u32 %3," KB ",%3\n\t"

// Dual keyed threefry (keys KG2), x1 inputs pre-offset by +K1.
__device__ __forceinline__ void tf20x2(uint32_t x1a, uint32_t x1b,
                                       uint32_t& ba, uint32_t& bb) {
  uint32_t x0a, x0b;
  asm("v_add_u32 %0,%4,%1\n\t" "v_add_u32 %2,%4,%3\n\t"
      "v_alignbit_b32 %1,%1,%1,19\n\t" "v_alignbit_b32 %3,%3,%3,19\n\t"
      "v_xor_b32 %1,%1,%0\n\t" "v_xor_b32 %3,%3,%2\n\t"
      TFR2("17") TFR2("6") TFR2("26")
      INJ2("%5", "%7")
      TFR2("15") TFR2("3") TFR2("16") TFR2("8")
      INJ2("%6", "%8")
      TFR2("19") TFR2("17") TFR2("6") TFR2("26")
      INJ2("%4", "%9")
      TFR2("15") TFR2("3") TFR2("16") TFR2("8")
      INJ2("%5", "%10")
      TFR2("19") TFR2("17") TFR2("6") TFR2("26")
      INJ2("%6", "%11")
      "v_xor_b32 %1,%1,%0\n\t" "v_xor_b32 %3,%3,%2\n\t"
      : "=&v"(x0a), "+v"(x1a), "=&v"(x0b), "+v"(x1b)
      : "s"(K0), "s"(K1), "s"(KS2), "s"(C1), "s"(C2), "s"(C3), "s"(C4), "s"(C5));
  ba = x1a; bb = x1b;
}

__device__ __forceinline__ float fast_log2(float x) {
  float r; asm("v_log_f32 %0, %1" : "=v"(r) : "v"(x)); return r;
}
__device__ __forceinline__ float fast_exp2(float x) {
  float r; asm("v_exp_f32 %0, %1" : "=v"(r) : "v"(x)); return r;
}
__device__ __forceinline__ float rcp_neg(float x) {   // 1/(-x)
  float r; asm("v_rcp_f32_e64 %0, -%1" : "=v"(r) : "v"(x)); return r;
}
__device__ __forceinline__ float fast_tanh(float w) {  // (t-1)/(t+1), t=e^2w
  float t = fast_exp2(w * 2.8853900817779268f);
  return (t - 1.0f) / (t + 1.0f);
}

// ---- g1 path (cold, 1 call/thread) ----
__device__ __forceinline__ uint32_t rotl(uint32_t x, int r) {
  return __builtin_rotateleft32(x, (unsigned)r);
}
__device__ __forceinline__ uint32_t tf_bits_g1(uint32_t e) {
  const uint32_t k0 = KG1.a, k1 = KG1.b;
  const uint32_t ks2 = k0 ^ k1 ^ 0x1BD11BDAu;
  uint32_t x0 = k0, x1 = e + k1;
#define TF_RND(r) { x0 += x1; x1 = rotl(x1, (r)); x1 ^= x0; }
  TF_RND(13) TF_RND(15) TF_RND(26) TF_RND(6)
  x0 += k1;  x1 += ks2 + 1u;
  TF_RND(17) TF_RND(29) TF_RND(16) TF_RND(24)
  x0 += ks2; x1 += k0 + 2u;
  TF_RND(13) TF_RND(15) TF_RND(26) TF_RND(6)
  x0 += k0;  x1 += k1 + 3u;
  TF_RND(17) TF_RND(29) TF_RND(16) TF_RND(24)
  x0 += k1;  x1 += ks2 + 4u;
  TF_RND(13) TF_RND(15) TF_RND(26) TF_RND(6)
  x0 += ks2; x1 += k0 + 5u;
#undef TF_RND
  return x0 ^ x1;
}
__device__ __forceinline__ float neglog2_from_bits(uint32_t bits) {
  float f  = __uint_as_float((bits >> 9) | 0x3f800000u) - 1.0f;
  float l1 = fast_log2(f);
  float nl = fmaxf(-l1, 1e-37f);
  return fast_log2(nl);
}

// grid: 4096 blocks = 512 o x 8 bgroups; 512 threads (8 waves); 4 rows/wave.
// 32768 waves = 4x device wave capacity -> scheduling slack + load balance.
__global__ __launch_bounds__(512) void k_fused(const float* __restrict__ x,
                                               const float* __restrict__ weight,
                                               const float* __restrict__ logits,
                                               float* __restrict__ out) {
  const int o    = blockIdx.x & 511;
  const int bg   = blockIdx.x >> 9;   // 0..7
  const int tid  = threadIdx.x;       // 0..511
  const int lane = tid & 63;
  const int wid  = tid >> 6;          // 0..7
  const float* lrow = logits + o * 512;

  // ---- phase 1: i* = argmax_i(logits[o,i] + g1[o,i]); 1 sample/thread ----
  float v; int idx;
  {
    const uint32_t e0 = (uint32_t)(o * 512 + tid);
    float g1a = fmaf(-0.69314718056f, neglog2_from_bits(tf_bits_g1(e0)),
                     0.3665129206f);
    v   = lrow[tid] + g1a;
    idx = tid;
  }
  for (int off = 32; off > 0; off >>= 1) {
    float ov = __shfl_down(v, off);
    int   oi = __shfl_down(idx, off);
    if (ov > v || (ov == v && oi < idx)) { v = ov; idx = oi; }
  }
  __shared__ float swv[8];
  __shared__ int   swi[8];
  __shared__ int   s_istar;
  __shared__ float s_c;
  if (lane == 0) { swv[wid] = v; swi[wid] = idx; }
  __syncthreads();
  if (tid == 0) {
    float bv = swv[0]; int bi = swi[0];
    for (int w = 1; w < 8; ++w)
      if (swv[w] > bv || (swv[w] == bv && swi[w] < bi)) { bv = swv[w]; bi = swi[w]; }
    s_istar = bi;
    s_c = 2.0f * fast_tanh(2.0f * fast_tanh(weight[o * 512 + bi]));
  }
  __syncthreads();
  const int   isel = s_istar;
  const float c    = s_c;

  // ---- block-constant per-sample scale: el_j = exp2(l*log2e + log2(1/ln2)) ----
  const float LOG2E = 1.4426950408889634f, CADD = 0.5287663729f;
  float el0 = fast_exp2(fmaf(lrow[lane      ], LOG2E, CADD));
  float el1 = fast_exp2(fmaf(lrow[lane +  64], LOG2E, CADD));
  float el2 = fast_exp2(fmaf(lrow[lane + 128], LOG2E, CADD));
  float el3 = fast_exp2(fmaf(lrow[lane + 192], LOG2E, CADD));
  float el4 = fast_exp2(fmaf(lrow[lane + 256], LOG2E, CADD));
  float el5 = fast_exp2(fmaf(lrow[lane + 320], LOG2E, CADD));
  float el6 = fast_exp2(fmaf(lrow[lane + 384], LOG2E, CADD));
  float el7 = fast_exp2(fmaf(lrow[lane + 448], LOG2E, CADD));

  const bool hit0 = (lane       == isel);
  const bool hit1 = (lane +  64 == isel);
  const bool hit2 = (lane + 128 == isel);
  const bool hit3 = (lane + 192 == isel);
  const bool hit4 = (lane + 256 == isel);
  const bool hit5 = (lane + 320 == isel);
  const bool hit6 = (lane + 384 == isel);
  const bool hit7 = (lane + 448 == isel);

  // ---- phase 2: 4 rows per wave ----
  const int b0 = bg * 32 + wid * 4;
#pragma unroll 1
  for (int it = 0; it < 4; ++it) {
    const int b   = b0 + it;                   // 0..255
    const int row = (b << 9) | o;              // 0..131071
    const uint32_t base = (uint32_t)row << 9;  // < 2^26
    const uint32_t ekrow = base + (uint32_t)lane + K1;  // x1 init = e + K1

    float sum = 0.0f, selv = 0.0f;
#define G2_PAIR(JA, ELA, HA, ELB, HB)                                \
    {                                                                \
      uint32_t bA, bB;                                               \
      tf20x2(ekrow + 128u * (JA), ekrow + 128u * (JA) + 64u, bA, bB);\
      float fA = __uint_as_float((bA >> 9) | 0x3f800000u) - 1.0f;    \
      float fB = __uint_as_float((bB >> 9) | 0x3f800000u) - 1.0f;    \
      float evA = (ELA) * rcp_neg(fast_log2(fA));                    \
      float evB = (ELB) * rcp_neg(fast_log2(fB));                    \
      sum += evA; selv = (HA) ? evA : selv;                          \
      sum += evB; selv = (HB) ? evB : selv;                          \
    }
    G2_PAIR(0, el0, hit0, el1, hit1)
    G2_PAIR(1, el2, hit2, el3, hit3)
    G2_PAIR(2, el4, hit4, el5, hit5)
    G2_PAIR(3, el6, hit6, el7, hit7)
#undef G2_PAIR
    for (int off = 32; off > 0; off >>= 1) sum += __shfl_down(sum, off);
    selv = __shfl(selv, isel & 63);            // exactly one lane holds it
    if (lane == 0) out[row] = c * x[(b << 9) | isel] * selv / sum;
  }
}

extern "C" void kernel_launch(void* const* d_in, const int* in_sizes, int n_in,
                              void* d_out, int out_size, void* d_ws, size_t ws_size,
                              hipStream_t stream) {
  const float* x      = (const float*)d_in[0];
  const float* weight = (const float*)d_in[1];
  const float* logits = (const float*)d_in[2];
  float* out = (float*)d_out;
  k_fused<<<dim3(512 * 8), dim3(512), 0, stream>>>(x, weight, logits, out);
}

// Round 19
// 152.347 us; speedup vs baseline: 1.0286x; 1.0286x over previous
//
#include <hip/hip_runtime.h>
#include <stdint.h>

// Issue-bound ladder: r15 198 -> r16 172 (asm threefry) -> r17 167 (rcp trick)
// -> r18 null (occupancy 78% didn't help; VALUBusy ~95% at 55% AND 78% occ).
// Model: t ~= 2.1us x instr/sample, threefry-20 (71 instr) irreducible for
// JAX-bit-exact bits. THIS ROUND: last epilogue trims (-2/sample):
//  (1) f-construction in asm: alignbit(127,bits,9) + subrev 1.0 (replaces 3 ops)
//  (2) fmac fuse: sum = fmaf(el_j, r, sum); hit-select r; el_sel hoisted.
// Grid = r17 shape (2048x256, 16 rows/wave — best scored config).
// All transcendentals raw-ISA asm — libm compile hangs on this pod.

struct U2 { uint32_t a, b; };
constexpr uint32_t crotl(uint32_t x, int r) { return (x << r) | (x >> (32 - r)); }

constexpr U2 ctf(uint32_t k0, uint32_t k1, uint32_t x0, uint32_t x1) {
  const uint32_t ks2 = k0 ^ k1 ^ 0x1BD11BDAu;
  x0 += k0; x1 += k1;
  x0 += x1; x1 = crotl(x1, 13); x1 ^= x0;
  x0 += x1; x1 = crotl(x1, 15); x1 ^= x0;
  x0 += x1; x1 = crotl(x1, 26); x1 ^= x0;
  x0 += x1; x1 = crotl(x1, 6);  x1 ^= x0;
  x0 += k1;  x1 += ks2 + 1u;
  x0 += x1; x1 = crotl(x1, 17); x1 ^= x0;
  x0 += x1; x1 = crotl(x1, 29); x1 ^= x0;
  x0 += x1; x1 = crotl(x1, 16); x1 ^= x0;
  x0 += x1; x1 = crotl(x1, 24); x1 ^= x0;
  x0 += ks2; x1 += k0 + 2u;
  x0 += x1; x1 = crotl(x1, 13); x1 ^= x0;
  x0 += x1; x1 = crotl(x1, 15); x1 ^= x0;
  x0 += x1; x1 = crotl(x1, 26); x1 ^= x0;
  x0 += x1; x1 = crotl(x1, 6);  x1 ^= x0;
  x0 += k0;  x1 += k1 + 3u;
  x0 += x1; x1 = crotl(x1, 17); x1 ^= x0;
  x0 += x1; x1 = crotl(x1, 29); x1 ^= x0;
  x0 += x1; x1 = crotl(x1, 16); x1 ^= x0;
  x0 += x1; x1 = crotl(x1, 24); x1 ^= x0;
  x0 += k1;  x1 += ks2 + 4u;
  x0 += x1; x1 = crotl(x1, 13); x1 ^= x0;
  x0 += x1; x1 = crotl(x1, 15); x1 ^= x0;
  x0 += x1; x1 = crotl(x1, 26); x1 ^= x0;
  x0 += x1; x1 = crotl(x1, 6);  x1 ^= x0;
  x0 += ks2; x1 += k0 + 5u;
  return U2{x0, x1};
}

constexpr U2 KG1 = ctf(0u, 42u, 0u, 0u);   // g1 (OUT,IN)
constexpr U2 KG2 = ctf(0u, 42u, 0u, 1u);   // g2 (B,OUT,IN)
constexpr uint32_t K0  = KG2.a, K1 = KG2.b;
constexpr uint32_t KS2 = K0 ^ K1 ^ 0x1BD11BDAu;
constexpr uint32_t C1 = KS2 + 1u, C2 = K0 + 2u, C3 = K1 + 3u,
                   C4 = KS2 + 4u, C5 = K0 + 5u;

#define TFR2(S) \
  "v_add_u32 %0,%0,%1\n\t" "v_add_u32 %2,%2,%3\n\t" \
  "v_alignbit_b32 %1,%1,%1," S "\n\t" "v_alignbit_b32 %3,%3,%3," S "\n\t" \
  "v_xor_b32 %1,%1,%0\n\t" "v_xor_b32 %3,%3,%2\n\t"
#define INJ2(KA, KB) \
  "v_add_u32 %0," KA ",%0\n\t" "v_add_u32 %2," KA ",%2\n\t" \
  "v_add_u32 %1," KB ",%1\n\t" "v_add_u32 %3," KB ",%3\n\t"

// Dual keyed threefry (keys KG2), x1 inputs pre-offset by +K1.
// Returns u = float((bits>>9)|0x3f800000) - 1.0f for both chains, built
// in-asm: alignbit(127, bits, 9) then v_subrev_f32 with inline 1.0.
__device__ __forceinline__ void tf20x2f(uint32_t x1a, uint32_t x1b,
                                        float& fa, float& fb) {
  uint32_t ra = x1a, rb = x1b, x0a, x0b;
  asm("v_add_u32 %0,%4,%1\n\t" "v_add_u32 %2,%4,%3\n\t"
      "v_alignbit_b32 %1,%1,%1,19\n\t" "v_alignbit_b32 %3,%3,%3,19\n\t"
      "v_xor_b32 %1,%1,%0\n\t" "v_xor_b32 %3,%3,%2\n\t"
      TFR2("17") TFR2("6") TFR2("26")
      INJ2("%5", "%7")
      TFR2("15") TFR2("3") TFR2("16") TFR2("8")
      INJ2("%6", "%8")
      TFR2("19") TFR2("17") TFR2("6") TFR2("26")
      INJ2("%4", "%9")
      TFR2("15") TFR2("3") TFR2("16") TFR2("8")
      INJ2("%5", "%10")
      TFR2("19") TFR2("17") TFR2("6") TFR2("26")
      INJ2("%6", "%11")
      "v_xor_b32 %1,%1,%0\n\t" "v_xor_b32 %3,%3,%2\n\t"   // bits = o0^o1
      "v_alignbit_b32 %1,%12,%1,9\n\t"                    // (127<<23)|(bits>>9)
      "v_alignbit_b32 %3,%12,%3,9\n\t"
      "v_subrev_f32 %1,1.0,%1\n\t"                        // f = u - 1.0
      "v_subrev_f32 %3,1.0,%3\n\t"
      : "=&v"(x0a), "+v"(ra), "=&v"(x0b), "+v"(rb)
      : "s"(K0), "s"(K1), "s"(KS2), "s"(C1), "s"(C2), "s"(C3), "s"(C4),
        "s"(C5), "s"(127u));
  fa = __uint_as_float(ra); fb = __uint_as_float(rb);
}

__device__ __forceinline__ float fast_log2(float x) {
  float r; asm("v_log_f32 %0, %1" : "=v"(r) : "v"(x)); return r;
}
__device__ __forceinline__ float fast_exp2(float x) {
  float r; asm("v_exp_f32 %0, %1" : "=v"(r) : "v"(x)); return r;
}
__device__ __forceinline__ float rcp_neg(float x) {   // 1/(-x)
  float r; asm("v_rcp_f32_e64 %0, -%1" : "=v"(r) : "v"(x)); return r;
}
__device__ __forceinline__ float fast_tanh(float w) {  // (t-1)/(t+1), t=e^2w
  float t = fast_exp2(w * 2.8853900817779268f);
  return (t - 1.0f) / (t + 1.0f);
}

// ---- g1 path (cold, 2 calls/thread) — byte-identical to r16/r17 ----
__device__ __forceinline__ uint32_t rotl(uint32_t x, int r) {
  return __builtin_rotateleft32(x, (unsigned)r);
}
__device__ __forceinline__ uint32_t tf_bits_g1(uint32_t e) {
  const uint32_t k0 = KG1.a, k1 = KG1.b;
  const uint32_t ks2 = k0 ^ k1 ^ 0x1BD11BDAu;
  uint32_t x0 = k0, x1 = e + k1;
#define TF_RND(r) { x0 += x1; x1 = rotl(x1, (r)); x1 ^= x0; }
  TF_RND(13) TF_RND(15) TF_RND(26) TF_RND(6)
  x0 += k1;  x1 += ks2 + 1u;
  TF_RND(17) TF_RND(29) TF_RND(16) TF_RND(24)
  x0 += ks2; x1 += k0 + 2u;
  TF_RND(13) TF_RND(15) TF_RND(26) TF_RND(6)
  x0 += k0;  x1 += k1 + 3u;
  TF_RND(17) TF_RND(29) TF_RND(16) TF_RND(24)
  x0 += k1;  x1 += ks2 + 4u;
  TF_RND(13) TF_RND(15) TF_RND(26) TF_RND(6)
  x0 += ks2; x1 += k0 + 5u;
#undef TF_RND
  return x0 ^ x1;
}
__device__ __forceinline__ float neglog2_from_bits(uint32_t bits) {
  float f  = __uint_as_float((bits >> 9) | 0x3f800000u) - 1.0f;
  float l1 = fast_log2(f);
  float nl = fmaxf(-l1, 1e-37f);
  return fast_log2(nl);
}

// grid: 2048 blocks = 512 o x 4 bgroups; 256 threads (4 waves); 16 rows/wave.
__global__ __launch_bounds__(256) void k_fused(const float* __restrict__ x,
                                               const float* __restrict__ weight,
                                               const float* __restrict__ logits,
                                               float* __restrict__ out) {
  const int o    = blockIdx.x & 511;
  const int bg   = blockIdx.x >> 9;   // 0..3
  const int tid  = threadIdx.x;
  const int lane = tid & 63;
  const int wid  = tid >> 6;
  const float* lrow = logits + o * 512;

  // ---- phase 1 (block-cooperative): i* = argmax_i(logits[o,i] + g1[o,i]) ----
  float v; int idx;
  {
    const uint32_t e0 = (uint32_t)(o * 512 + tid);
    float g1a = fmaf(-0.69314718056f, neglog2_from_bits(tf_bits_g1(e0)),
                     0.3665129206f);
    v   = lrow[tid] + g1a;
    idx = tid;
    float g1b = fmaf(-0.69314718056f, neglog2_from_bits(tf_bits_g1(e0 + 256u)),
                     0.3665129206f);
    float v2 = lrow[tid + 256] + g1b;
    if (v2 > v) { v = v2; idx = tid + 256; }  // tie -> lower index (jnp.argmax)
  }
  for (int off = 32; off > 0; off >>= 1) {
    float ov = __shfl_down(v, off);
    int   oi = __shfl_down(idx, off);
    if (ov > v || (ov == v && oi < idx)) { v = ov; idx = oi; }
  }
  __shared__ float swv[4];
  __shared__ int   swi[4];
  __shared__ int   s_istar;
  __shared__ float s_c;
  if (lane == 0) { swv[wid] = v; swi[wid] = idx; }
  __syncthreads();
  if (tid == 0) {
    float bv = swv[0]; int bi = swi[0];
    for (int w = 1; w < 4; ++w)
      if (swv[w] > bv || (swv[w] == bv && swi[w] < bi)) { bv = swv[w]; bi = swi[w]; }
    s_istar = bi;
    s_c = 2.0f * fast_tanh(2.0f * fast_tanh(weight[o * 512 + bi]));
  }
  __syncthreads();
  const int   isel = s_istar;
  const float c    = s_c;

  // ---- block-constant per-sample scale: el_j = exp2(l*log2e + log2(1/ln2)) ----
  const float LOG2E = 1.4426950408889634f, CADD = 0.5287663729f;
  float el0 = fast_exp2(fmaf(lrow[lane      ], LOG2E, CADD));
  float el1 = fast_exp2(fmaf(lrow[lane +  64], LOG2E, CADD));
  float el2 = fast_exp2(fmaf(lrow[lane + 128], LOG2E, CADD));
  float el3 = fast_exp2(fmaf(lrow[lane + 192], LOG2E, CADD));
  float el4 = fast_exp2(fmaf(lrow[lane + 256], LOG2E, CADD));
  float el5 = fast_exp2(fmaf(lrow[lane + 320], LOG2E, CADD));
  float el6 = fast_exp2(fmaf(lrow[lane + 384], LOG2E, CADD));
  float el7 = fast_exp2(fmaf(lrow[lane + 448], LOG2E, CADD));

  const bool hit0 = (lane       == isel);
  const bool hit1 = (lane +  64 == isel);
  const bool hit2 = (lane + 128 == isel);
  const bool hit3 = (lane + 192 == isel);
  const bool hit4 = (lane + 256 == isel);
  const bool hit5 = (lane + 320 == isel);
  const bool hit6 = (lane + 384 == isel);
  const bool hit7 = (lane + 448 == isel);
  // loop-invariant: el at this lane's hit slot (only meaningful on hit lane)
  const float el_sel = hit0 ? el0 : hit1 ? el1 : hit2 ? el2 : hit3 ? el3
                     : hit4 ? el4 : hit5 ? el5 : hit6 ? el6 : el7;

  // ---- phase 2: 16 rows per wave, dual-chain pairs ----
  const int b0 = bg * 64 + wid * 16;
#pragma unroll 1
  for (int it = 0; it < 16; ++it) {
    const int b   = b0 + it;                   // 0..255
    const int row = (b << 9) | o;              // 0..131071
    const uint32_t base = (uint32_t)row << 9;  // < 2^26
    const uint32_t ekrow = base + (uint32_t)lane + K1;  // x1 init = e + K1

    float sum = 0.0f, rsel = 0.0f;
#define G2_PAIR(JA, ELA, HA, ELB, HB)                                \
    {                                                                \
      float fA, fB;                                                  \
      tf20x2f(ekrow + 128u * (JA), ekrow + 128u * (JA) + 64u, fA, fB);\
      float rA = rcp_neg(fast_log2(fA));                             \
      float rB = rcp_neg(fast_log2(fB));                             \
      sum = fmaf((ELA), rA, sum); rsel = (HA) ? rA : rsel;           \
      sum = fmaf((ELB), rB, sum); rsel = (HB) ? rB : rsel;           \
    }
    G2_PAIR(0, el0, hit0, el1, hit1)
    G2_PAIR(1, el2, hit2, el3, hit3)
    G2_PAIR(2, el4, hit4, el5, hit5)
    G2_PAIR(3, el6, hit6, el7, hit7)
#undef G2_PAIR
    float vsel = el_sel * rsel;                // true selv on the hit lane
    for (int off = 32; off > 0; off >>= 1) sum += __shfl_down(sum, off);
    vsel = __shfl(vsel, isel & 63);            // exactly one lane holds it
    if (lane == 0) out[row] = c * x[(b << 9) | isel] * vsel / sum;
  }
}

extern "C" void kernel_launch(void* const* d_in, const int* in_sizes, int n_in,
                              void* d_out, int out_size, void* d_ws, size_t ws_size,
                              hipStream_t stream) {
  const float* x      = (const float*)d_in[0];
  const float* weight = (const float*)d_in[1];
  const float* logits = (const float*)d_in[2];
  float* out = (float*)d_out;
  k_fused<<<dim3(512 * 4), dim3(256), 0, stream>>>(x, weight, logits, out);
}

// Round 20
// 145.669 us; speedup vs baseline: 1.0758x; 1.0458x over previous
//
#include <hip/hip_runtime.h>
#include <stdint.h>

// Issue-bound ladder: 198 (r15) -> 172 (asm threefry) -> 167 (rcp trick) ->
// 165 (asm float-construct + fmac). Model t ~= 2.1us x instr/sample validated
// 5 rounds running (ILP null, occupancy null => pure issue-bound).
// THIS ROUND: threefry injection/round fusion via v_add3_u32 at the 4 interior
// group boundaries: {x0+=ka; x0+=x1'} -> v_add3_u32(x0,x1',ka). -4 instr/chain
// (73->69, -5.5% of stream). Bit-exact same RNG (verified absmax 3.814697e-6).
// All transcendentals raw-ISA asm — libm compile hangs on this pod.

struct U2 { uint32_t a, b; };
constexpr uint32_t crotl(uint32_t x, int r) { return (x << r) | (x >> (32 - r)); }

constexpr U2 ctf(uint32_t k0, uint32_t k1, uint32_t x0, uint32_t x1) {
  const uint32_t ks2 = k0 ^ k1 ^ 0x1BD11BDAu;
  x0 += k0; x1 += k1;
  x0 += x1; x1 = crotl(x1, 13); x1 ^= x0;
  x0 += x1; x1 = crotl(x1, 15); x1 ^= x0;
  x0 += x1; x1 = crotl(x1, 26); x1 ^= x0;
  x0 += x1; x1 = crotl(x1, 6);  x1 ^= x0;
  x0 += k1;  x1 += ks2 + 1u;
  x0 += x1; x1 = crotl(x1, 17); x1 ^= x0;
  x0 += x1; x1 = crotl(x1, 29); x1 ^= x0;
  x0 += x1; x1 = crotl(x1, 16); x1 ^= x0;
  x0 += x1; x1 = crotl(x1, 24); x1 ^= x0;
  x0 += ks2; x1 += k0 + 2u;
  x0 += x1; x1 = crotl(x1, 13); x1 ^= x0;
  x0 += x1; x1 = crotl(x1, 15); x1 ^= x0;
  x0 += x1; x1 = crotl(x1, 26); x1 ^= x0;
  x0 += x1; x1 = crotl(x1, 6);  x1 ^= x0;
  x0 += k0;  x1 += k1 + 3u;
  x0 += x1; x1 = crotl(x1, 17); x1 ^= x0;
  x0 += x1; x1 = crotl(x1, 29); x1 ^= x0;
  x0 += x1; x1 = crotl(x1, 16); x1 ^= x0;
  x0 += x1; x1 = crotl(x1, 24); x1 ^= x0;
  x0 += k1;  x1 += ks2 + 4u;
  x0 += x1; x1 = crotl(x1, 13); x1 ^= x0;
  x0 += x1; x1 = crotl(x1, 15); x1 ^= x0;
  x0 += x1; x1 = crotl(x1, 26); x1 ^= x0;
  x0 += x1; x1 = crotl(x1, 6);  x1 ^= x0;
  x0 += ks2; x1 += k0 + 5u;
  return U2{x0, x1};
}

constexpr U2 KG1 = ctf(0u, 42u, 0u, 0u);   // g1 (OUT,IN)
constexpr U2 KG2 = ctf(0u, 42u, 0u, 1u);   // g2 (B,OUT,IN)
constexpr uint32_t K0  = KG2.a, K1 = KG2.b;
constexpr uint32_t KS2 = K0 ^ K1 ^ 0x1BD11BDAu;
constexpr uint32_t C1 = KS2 + 1u, C2 = K0 + 2u, C3 = K1 + 3u,
                   C4 = KS2 + 4u, C5 = K0 + 5u;

// plain round for both chains (shift S = 32 - rot)
#define TFR2(S) \
  "v_add_u32 %0,%0,%1\n\t" "v_add_u32 %2,%2,%3\n\t" \
  "v_alignbit_b32 %1,%1,%1," S "\n\t" "v_alignbit_b32 %3,%3,%3," S "\n\t" \
  "v_xor_b32 %1,%1,%0\n\t" "v_xor_b32 %3,%3,%2\n\t"
// fused boundary: x1 += KB; x0 = add3(x0, x1, KA); rot; xor   (= injection+round)
#define BND2(KA, KB, S) \
  "v_add_u32 %1," KB ",%1\n\t" "v_add_u32 %3," KB ",%3\n\t" \
  "v_add3_u32 %0,%0,%1," KA "\n\t" "v_add3_u32 %2,%2,%3," KA "\n\t" \
  "v_alignbit_b32 %1,%1,%1," S "\n\t" "v_alignbit_b32 %3,%3,%3," S "\n\t" \
  "v_xor_b32 %1,%1,%0\n\t" "v_xor_b32 %3,%3,%2\n\t"

// Dual keyed threefry (keys KG2), x1 inputs pre-offset by +K1; returns
// f = float((bits>>9)|0x3f800000) - 1.0f for both chains.
__device__ __forceinline__ void tf20x2f(uint32_t x1a, uint32_t x1b,
                                        float& fa, float& fb) {
  uint32_t ra = x1a, rb = x1b, x0a, x0b;
  asm(// R1 (x0-init fold: x0 = K0 + x1), rot 13 -> shift 19
      "v_add_u32 %0,%4,%1\n\t" "v_add_u32 %2,%4,%3\n\t"
      "v_alignbit_b32 %1,%1,%1,19\n\t" "v_alignbit_b32 %3,%3,%3,19\n\t"
      "v_xor_b32 %1,%1,%0\n\t" "v_xor_b32 %3,%3,%2\n\t"
      TFR2("17") TFR2("6") TFR2("26")    // R2-R4 (rot 15,26,6)
      BND2("%5", "%7", "15")             // R5: inject (K1, C1), rot 17
      TFR2("3") TFR2("16") TFR2("8")     // R6-R8 (rot 29,16,24)
      BND2("%6", "%8", "19")             // R9: inject (KS2, C2), rot 13
      TFR2("17") TFR2("6") TFR2("26")    // R10-R12 (rot 15,26,6)
      BND2("%4", "%9", "15")             // R13: inject (K0, C3), rot 17
      TFR2("3") TFR2("16") TFR2("8")     // R14-R16 (rot 29,16,24)
      BND2("%5", "%10", "19")            // R17: inject (K1, C4), rot 13
      TFR2("17") TFR2("6") TFR2("26")    // R18-R20 (rot 15,26,6)
      // final injection + fold + float-construct
      "v_add_u32 %0,%6,%0\n\t" "v_add_u32 %2,%6,%2\n\t"   // x0 += KS2
      "v_add_u32 %1,%11,%1\n\t" "v_add_u32 %3,%11,%3\n\t" // x1 += C5
      "v_xor_b32 %1,%1,%0\n\t" "v_xor_b32 %3,%3,%2\n\t"   // bits = o0^o1
      "v_alignbit_b32 %1,%12,%1,9\n\t"                    // (127<<23)|(bits>>9)
      "v_alignbit_b32 %3,%12,%3,9\n\t"
      "v_subrev_f32 %1,1.0,%1\n\t"                        // f = u - 1.0
      "v_subrev_f32 %3,1.0,%3\n\t"
      : "=&v"(x0a), "+v"(ra), "=&v"(x0b), "+v"(rb)
      : "s"(K0), "s"(K1), "s"(KS2), "s"(C1), "s"(C2), "s"(C3), "s"(C4),
        "s"(C5), "s"(127u));
  fa = __uint_as_float(ra); fb = __uint_as_float(rb);
}

__device__ __forceinline__ float fast_log2(float x) {
  float r; asm("v_log_f32 %0, %1" : "=v"(r) : "v"(x)); return r;
}
__device__ __forceinline__ float fast_exp2(float x) {
  float r; asm("v_exp_f32 %0, %1" : "=v"(r) : "v"(x)); return r;
}
__device__ __forceinline__ float rcp_neg(float x) {   // 1/(-x)
  float r; asm("v_rcp_f32_e64 %0, -%1" : "=v"(r) : "v"(x)); return r;
}
__device__ __forceinline__ float fast_tanh(float w) {  // (t-1)/(t+1), t=e^2w
  float t = fast_exp2(w * 2.8853900817779268f);
  return (t - 1.0f) / (t + 1.0f);
}

// ---- g1 path (cold, 2 calls/thread) — byte-identical to r16-r19 ----
__device__ __forceinline__ uint32_t rotl(uint32_t x, int r) {
  return __builtin_rotateleft32(x, (unsigned)r);
}
__device__ __forceinline__ uint32_t tf_bits_g1(uint32_t e) {
  const uint32_t k0 = KG1.a, k1 = KG1.b;
  const uint32_t ks2 = k0 ^ k1 ^ 0x1BD11BDAu;
  uint32_t x0 = k0, x1 = e + k1;
#define TF_RND(r) { x0 += x1; x1 = rotl(x1, (r)); x1 ^= x0; }
  TF_RND(13) TF_RND(15) TF_RND(26) TF_RND(6)
  x0 += k1;  x1 += ks2 + 1u;
  TF_RND(17) TF_RND(29) TF_RND(16) TF_RND(24)
  x0 += ks2; x1 += k0 + 2u;
  TF_RND(13) TF_RND(15) TF_RND(26) TF_RND(6)
  x0 += k0;  x1 += k1 + 3u;
  TF_RND(17) TF_RND(29) TF_RND(16) TF_RND(24)
  x0 += k1;  x1 += ks2 + 4u;
  TF_RND(13) TF_RND(15) TF_RND(26) TF_RND(6)
  x0 += ks2; x1 += k0 + 5u;
#undef TF_RND
  return x0 ^ x1;
}
__device__ __forceinline__ float neglog2_from_bits(uint32_t bits) {
  float f  = __uint_as_float((bits >> 9) | 0x3f800000u) - 1.0f;
  float l1 = fast_log2(f);
  float nl = fmaxf(-l1, 1e-37f);
  return fast_log2(nl);
}

// grid: 2048 blocks = 512 o x 4 bgroups; 256 threads (4 waves); 16 rows/wave.
__global__ __launch_bounds__(256) void k_fused(const float* __restrict__ x,
                                               const float* __restrict__ weight,
                                               const float* __restrict__ logits,
                                               float* __restrict__ out) {
  const int o    = blockIdx.x & 511;
  const int bg   = blockIdx.x >> 9;   // 0..3
  const int tid  = threadIdx.x;
  const int lane = tid & 63;
  const int wid  = tid >> 6;
  const float* lrow = logits + o * 512;

  // ---- phase 1 (block-cooperative): i* = argmax_i(logits[o,i] + g1[o,i]) ----
  float v; int idx;
  {
    const uint32_t e0 = (uint32_t)(o * 512 + tid);
    float g1a = fmaf(-0.69314718056f, neglog2_from_bits(tf_bits_g1(e0)),
                     0.3665129206f);
    v   = lrow[tid] + g1a;
    idx = tid;
    float g1b = fmaf(-0.69314718056f, neglog2_from_bits(tf_bits_g1(e0 + 256u)),
                     0.3665129206f);
    float v2 = lrow[tid + 256] + g1b;
    if (v2 > v) { v = v2; idx = tid + 256; }  // tie -> lower index (jnp.argmax)
  }
  for (int off = 32; off > 0; off >>= 1) {
    float ov = __shfl_down(v, off);
    int   oi = __shfl_down(idx, off);
    if (ov > v || (ov == v && oi < idx)) { v = ov; idx = oi; }
  }
  __shared__ float swv[4];
  __shared__ int   swi[4];
  __shared__ int   s_istar;
  __shared__ float s_c;
  if (lane == 0) { swv[wid] = v; swi[wid] = idx; }
  __syncthreads();
  if (tid == 0) {
    float bv = swv[0]; int bi = swi[0];
    for (int w = 1; w < 4; ++w)
      if (swv[w] > bv || (swv[w] == bv && swi[w] < bi)) { bv = swv[w]; bi = swi[w]; }
    s_istar = bi;
    s_c = 2.0f * fast_tanh(2.0f * fast_tanh(weight[o * 512 + bi]));
  }
  __syncthreads();
  const int   isel = s_istar;
  const float c    = s_c;

  // ---- block-constant per-sample scale: el_j = exp2(l*log2e + log2(1/ln2)) ----
  const float LOG2E = 1.4426950408889634f, CADD = 0.5287663729f;
  float el0 = fast_exp2(fmaf(lrow[lane      ], LOG2E, CADD));
  float el1 = fast_exp2(fmaf(lrow[lane +  64], LOG2E, CADD));
  float el2 = fast_exp2(fmaf(lrow[lane + 128], LOG2E, CADD));
  float el3 = fast_exp2(fmaf(lrow[lane + 192], LOG2E, CADD));
  float el4 = fast_exp2(fmaf(lrow[lane + 256], LOG2E, CADD));
  float el5 = fast_exp2(fmaf(lrow[lane + 320], LOG2E, CADD));
  float el6 = fast_exp2(fmaf(lrow[lane + 384], LOG2E, CADD));
  float el7 = fast_exp2(fmaf(lrow[lane + 448], LOG2E, CADD));

  const bool hit0 = (lane       == isel);
  const bool hit1 = (lane +  64 == isel);
  const bool hit2 = (lane + 128 == isel);
  const bool hit3 = (lane + 192 == isel);
  const bool hit4 = (lane + 256 == isel);
  const bool hit5 = (lane + 320 == isel);
  const bool hit6 = (lane + 384 == isel);
  const bool hit7 = (lane + 448 == isel);
  const float el_sel = hit0 ? el0 : hit1 ? el1 : hit2 ? el2 : hit3 ? el3
                     : hit4 ? el4 : hit5 ? el5 : hit6 ? el6 : el7;

  // ---- phase 2: 16 rows per wave, dual-chain pairs ----
  const int b0 = bg * 64 + wid * 16;
#pragma unroll 1
  for (int it = 0; it < 16; ++it) {
    const int b   = b0 + it;                   // 0..255
    const int row = (b << 9) | o;              // 0..131071
    const uint32_t base = (uint32_t)row << 9;  // < 2^26
    const uint32_t ekrow = base + (uint32_t)lane + K1;  // x1 init = e + K1

    float sum = 0.0f, rsel = 0.0f;
#define G2_PAIR(JA, ELA, HA, ELB, HB)                                \
    {                                                                \
      float fA, fB;                                                  \
      tf20x2f(ekrow + 128u * (JA), ekrow + 128u * (JA) + 64u, fA, fB);\
      float rA = rcp_neg(fast_log2(fA));                             \
      float rB = rcp_neg(fast_log2(fB));                             \
      sum = fmaf((ELA), rA, sum); rsel = (HA) ? rA : rsel;           \
      sum = fmaf((ELB), rB, sum); rsel = (HB) ? rB : rsel;           \
    }
    G2_PAIR(0, el0, hit0, el1, hit1)
    G2_PAIR(1, el2, hit2, el3, hit3)
    G2_PAIR(2, el4, hit4, el5, hit5)
    G2_PAIR(3, el6, hit6, el7, hit7)
#undef G2_PAIR
    float vsel = el_sel * rsel;                // true selv on the hit lane
    for (int off = 32; off > 0; off >>= 1) sum += __shfl_down(sum, off);
    vsel = __shfl(vsel, isel & 63);            // exactly one lane holds it
    if (lane == 0) out[row] = c * x[(b << 9) | isel] * vsel / sum;
  }
}

extern "C" void kernel_launch(void* const* d_in, const int* in_sizes, int n_in,
                              void* d_out, int out_size, void* d_ws, size_t ws_size,
                              hipStream_t stream) {
  const float* x      = (const float*)d_in[0];
  const float* weight = (const float*)d_in[1];
  const float* logits = (const float*)d_in[2];
  float* out = (float*)d_out;
  k_fused<<<dim3(512 * 4), dim3(256), 0, stream>>>(x, weight, logits, out);
}